// Round 8
// baseline (22.459 us; speedup 1.0000x reference)
//
#include <hip/hip_runtime.h>
#include <math.h>

typedef __attribute__((ext_vector_type(4))) float f32x4;

__device__ __forceinline__ float rcpf(float x){ return __builtin_amdgcn_rcpf(x); }

#define HS 68   // row stride (floats): 16B-aligned, uniform 4-lanes/bank for b128

__global__ __launch_bounds__(256, 4) void phys8(
    const float* __restrict__ x,
    const float* __restrict__ W1, const float* __restrict__ b1,
    const float* __restrict__ W2, const float* __restrict__ b2,
    const float* __restrict__ W3, const float* __restrict__ b3,
    const float* __restrict__ W4, const float* __restrict__ b4,
    const float* __restrict__ i0p, const float* __restrict__ alphap,
    float* __restrict__ out, int nrows)
{
    __shared__ __align__(16) float hbA[64*HS];
    __shared__ __align__(16) float hbB[64*HS];

    const int tid  = threadIdx.x;
    const int lane = tid & 63;                                  // row (whole kernel)
    const int wvu  = __builtin_amdgcn_readfirstlane(tid >> 6);  // 0..3 (uniform)
    const int c0   = 16*wvu;                                    // 16-col slice

    const int rowg = blockIdx.x*64 + lane;
    const int rowc = min(rowg, nrows-1);
    float xv[5];
#pragma unroll
    for (int i=0;i<5;i++) xv[i] = x[rowc*5+i];

    // ---- L1: 16 cols, nested-fmaf order (b + x0w0 + ... + x4w4), uniform weights ----
    float hs[16];
#pragma unroll
    for (int j=0;j<16;j++){
        int c = c0 + j;
        float hv = b1[c];
        hv = fmaf(xv[0], W1[0*64+c], hv);
        hv = fmaf(xv[1], W1[1*64+c], hv);
        hv = fmaf(xv[2], W1[2*64+c], hv);
        hv = fmaf(xv[3], W1[3*64+c], hv);
        hv = fmaf(xv[4], W1[4*64+c], hv);
        hs[j] = fmaxf(hv, 0.f);
    }

#define PUBLISH(BUF)                                                     \
    {                                                                    \
        _Pragma("unroll")                                                \
        for (int q=0;q<4;q++){                                           \
            f32x4 t; t.x=hs[4*q]; t.y=hs[4*q+1]; t.z=hs[4*q+2]; t.w=hs[4*q+3]; \
            *(f32x4*)&BUF[lane*HS + c0 + 4*q] = t;                       \
        }                                                                \
    }

    float h[64];
#define CONSUME(BUF)                                                     \
    {                                                                    \
        _Pragma("unroll")                                                \
        for (int q=0;q<16;q++){                                          \
            f32x4 t = *(const f32x4*)&BUF[lane*HS + 4*q];                \
            h[4*q]=t.x; h[4*q+1]=t.y; h[4*q+2]=t.z; h[4*q+3]=t.w;        \
        }                                                                \
    }

    // 64->64 layer: 16 cols/thread, single accumulator per col (16 parallel chains)
#define BIGLAYER(W, B)                                                   \
    {                                                                    \
        float acc[16];                                                   \
        _Pragma("unroll")                                                \
        for (int j=0;j<16;j++) acc[j] = B[c0+j];                         \
        _Pragma("unroll")                                                \
        for (int k=0;k<64;k++){                                          \
            _Pragma("unroll")                                            \
            for (int j=0;j<16;j++)                                       \
                acc[j] = fmaf(h[k], W[k*64 + c0 + j], acc[j]);           \
        }                                                                \
        _Pragma("unroll")                                                \
        for (int j=0;j<16;j++) hs[j] = fmaxf(acc[j], 0.f);               \
    }

    PUBLISH(hbA);            // h1 -> A
    __syncthreads();
    CONSUME(hbA);
    BIGLAYER(W2, b2);        // h2 slice
    PUBLISH(hbB);            // h2 -> B (A reads already done by this thread)
    __syncthreads();
    CONSUME(hbB);
    BIGLAYER(W3, b3);        // h3 slice
    PUBLISH(hbA);            // h3 -> A (all B... all A reads finished pre-barrier)
    __syncthreads();
    CONSUME(hbA);            // full h3 row in registers

    // ---- L4: 6 lat outputs per thread (reg-resident dot products) ----
    float lat[6];
#pragma unroll
    for (int c=0;c<6;c++){
        float a = b4[c];
#pragma unroll
        for (int k=0;k<64;k++) a = fmaf(h[k], W4[k*6+c], a);
        lat[c] = a;
    }

    // ---- epilogue (same as R6) ----
    const float KFRT = (float)(96485.33/(8.314*298.15));
    const float dV   = 1.25f/999.0f;
    const float ALP0 = alphap[0], ALP1 = alphap[1], ALP2 = alphap[2];
    const float IO0  = i0p[0],   IO1  = i0p[1],   IO2  = i0p[2];

    float rr   = 4e-8f * __expf(lat[0]);
    float epsv = rcpf(1.0f + __expf(-lat[1]));
    float Kdl  = __expf(lat[2]);
    float Deff = 1.91e-9f * epsv * sqrtf(epsv);
    float Kgdl = Kdl * Deff * rcpf(rr);
    float S    = rcpf(Kgdl) + fabsf(xv[3]) * rcpf((1.0f - epsv) * Deff);
    float il0  = S * (float)(1.0 / (2.0  * 96485.33 * 34.0));
    float il1  = S * (float)(1.0 / (12.0 * 96485.33 * 34.0));

    float t0s = 2.0f*lat[3], t1s = 2.0f*lat[4], t2s = 2.0f*lat[5];
    float mx = fmaxf(t0s, fmaxf(t1s, t2s));
    float e0 = __expf(t0s-mx), e1 = __expf(t1s-mx), e2 = __expf(t2s-mx);
    float se = e0 + e1 + e2;
    float it0 = se*rcpf(e0), it1 = se*rcpf(e1), it2 = se*rcpf(e2);

    // hoisted accurate divisions (1-ulp-class vs R6's table path)
    float M0 = it0 / IO0, M1 = it1 / IO1, M2 = it2 / IO2;
    float aK0 = ALP0*KFRT, aK1 = ALP1*KFRT, aK2 = ALP2*KFRT;

    // per-probe: table-entry-identical exp arguments (Vv = -1.25f + v*dV)
    auto itot = [&](int v) -> float {
        float Vv = -1.25f + (float)v*dV;
        float q0 = fmaf(expf(aK0*(Vv+0.11f)), M0, il0);
        float q1 = fmaf(expf(aK1*(Vv-0.08f)), M1, il1);
        float q2 = expf(aK2*Vv) * M2;
        return rcpf(q0) + rcpf(q1) + rcpf(q2);
    };

    // i_tot strictly decreasing in v; bisect to the crossing, values tracked.
    float f0   = itot(0);
    float f999 = itot(999);
    bool le0 = f0   <= 200.0f;
    bool le9 = f999 <= 200.0f;

    int lo = 0, hi = 999;
    float flo = f0, fhi = f999;
#pragma unroll 1
    for (int it = 0; it < 10; ++it){
        int mid = (lo + hi) >> 1;
        float fm = itot(mid);
        bool le = fm <= 200.0f;
        hi  = le ? mid : hi;
        fhi = le ? fm  : fhi;
        lo  = le ? lo  : mid;
        flo = le ? flo : fm;
    }
    float da = flo - 200.0f;        // > 0 under invariant
    float db = 200.0f - fhi;        // >= 0
    int idx = (da <= db) ? lo : hi; // tie -> earlier index (argmin-first)
    if (!le9) idx = 999;
    if (le0)  idx = 0;

    // selected currents -> faradaic efficiencies
    {
        float Vv = -1.25f + (float)idx*dV;
        float s0 = rcpf(fmaf(expf(aK0*(Vv+0.11f)), M0, il0));
        float s1 = rcpf(fmaf(expf(aK1*(Vv-0.08f)), M1, il1));
        float s2 = rcpf(expf(aK2*Vv) * M2);
        float inv = rcpf(s0 + s1 + s2);
        if (rowg < nrows){
            float2 o; o.x = s1*inv; o.y = s0*inv;
            reinterpret_cast<float2*>(out)[rowg] = o;
        }
    }
}

extern "C" void kernel_launch(void* const* d_in, const int* in_sizes, int n_in,
                              void* d_out, int out_size, void* d_ws, size_t ws_size,
                              hipStream_t stream) {
    (void)n_in; (void)d_ws; (void)ws_size; (void)out_size;
    int nrows = in_sizes[0] / 5;
    int nblk = (nrows + 63) / 64;
    phys8<<<dim3(nblk), dim3(256), 0, stream>>>(
        (const float*)d_in[0],
        (const float*)d_in[1], (const float*)d_in[2],
        (const float*)d_in[3], (const float*)d_in[4],
        (const float*)d_in[5], (const float*)d_in[6],
        (const float*)d_in[7], (const float*)d_in[8],
        (const float*)d_in[9], (const float*)d_in[10],
        (float*)d_out, nrows);
}

// Round 10
// 16.477 us; speedup vs baseline: 1.3630x; 1.3630x over previous
//
#include <hip/hip_runtime.h>
#include <math.h>

typedef __attribute__((ext_vector_type(4))) float f32x4;
typedef __attribute__((ext_vector_type(2))) float f32x2;

__device__ __forceinline__ float rcpf(float x){ return __builtin_amdgcn_rcpf(x); }

__global__ __launch_bounds__(1024, 4) void phys9(
    const float* __restrict__ x,
    const float* __restrict__ W1, const float* __restrict__ b1,
    const float* __restrict__ W2, const float* __restrict__ b2,
    const float* __restrict__ W3, const float* __restrict__ b3,
    const float* __restrict__ W4, const float* __restrict__ b4,
    const float* __restrict__ i0p, const float* __restrict__ alphap,
    float* __restrict__ out, int nrows)
{
    __shared__ __align__(16) f32x4 hb4[16][64];   // [k/4][row] quad-k exchange
    __shared__ __align__(16) float tab4[4000];    // [v][4] invbase per species
    __shared__ float latb[64*8];                  // [row][lat0..5, x3, -]

    const int tid  = threadIdx.x;
    const int lane = tid & 63;                                  // row within block
    const int wvu  = __builtin_amdgcn_readfirstlane(tid >> 6);  // wave 0..15 (uniform)
    const int c0   = 4*wvu;                                     // 4-col slice base

    // ---------------- prologue: voltage table ----------------
    {
        const float KFRT = (float)(96485.33/(8.314*298.15));
        const float dV = 1.25f/999.0f;
        float a0=alphap[0], a1=alphap[1], a2=alphap[2];
        float i00=i0p[0], i01=i0p[1], i02=i0p[2];
        for (int v = tid; v < 1000; v += 1024){
            float Vv = -1.25f + (float)v*dV;
            tab4[v*4+0] = expf(a0*KFRT*(Vv+0.11f))/i00;
            tab4[v*4+1] = expf(a1*KFRT*(Vv-0.08f))/i01;
            tab4[v*4+2] = expf(a2*KFRT*(Vv))/i02;
            tab4[v*4+3] = 0.f;
        }
    }

    // ---------------- MLP phase: lane = row, wave = 4-col slice ----------------
    const int rowg = blockIdx.x*64 + lane;
    const int rowc = min(rowg, nrows-1);
    float xv[5];
#pragma unroll
    for (int i=0;i<5;i++) xv[i] = x[rowc*5+i];
    if (wvu == 6) latb[lane*8+6] = xv[3];       // stash x3 for search phase

    // L1: nested-fmaf order (validated), uniform scalar weights
    f32x4 hsv;
#pragma unroll
    for (int j=0;j<4;j++){
        int c = c0 + j;
        float hv = b1[c];
        hv = fmaf(xv[0], W1[0*64+c], hv);
        hv = fmaf(xv[1], W1[1*64+c], hv);
        hv = fmaf(xv[2], W1[2*64+c], hv);
        hv = fmaf(xv[3], W1[3*64+c], hv);
        hv = fmaf(xv[4], W1[4*64+c], hv);
        hsv[j] = fmaxf(hv, 0.f);
    }

    f32x4 hq[16];   // full 64-value hidden row in registers

    // 64->64 layer: 2 packed-f32 chains (cols c0..c0+1, c0+2..c0+3), k ascending.
    // v_pk_fma_f32 is bitwise IEEE per element -> identical to R8's validated
    // single-chain-per-column order.
#define BIGLAYER(W, B)                                                     \
    {                                                                      \
        f32x2 aA = { B[c0],   B[c0+1] };                                   \
        f32x2 aB = { B[c0+2], B[c0+3] };                                   \
        _Pragma("unroll")                                                  \
        for (int k=0;k<64;k++){                                            \
            float hk = hq[k>>2][k&3];                                      \
            f32x2 hk2 = { hk, hk };                                        \
            f32x2 wA = *(const f32x2*)&W[k*64 + c0];                       \
            f32x2 wB = *(const f32x2*)&W[k*64 + c0 + 2];                   \
            aA = __builtin_elementwise_fma(hk2, wA, aA);                   \
            aB = __builtin_elementwise_fma(hk2, wB, aB);                   \
        }                                                                  \
        hsv[0]=fmaxf(aA.x,0.f); hsv[1]=fmaxf(aA.y,0.f);                    \
        hsv[2]=fmaxf(aB.x,0.f); hsv[3]=fmaxf(aB.y,0.f);                    \
    }

    hb4[wvu][lane] = hsv;          // publish h1 (one b128)
    __syncthreads();
#pragma unroll
    for (int q=0;q<16;q++) hq[q] = hb4[q][lane];
    __syncthreads();               // all reads done before h2 overwrite

    BIGLAYER(W2, b2);
    hb4[wvu][lane] = hsv;          // publish h2
    __syncthreads();
#pragma unroll
    for (int q=0;q<16;q++) hq[q] = hb4[q][lane];
    __syncthreads();               // all reads done before h3 overwrite

    BIGLAYER(W3, b3);
    hb4[wvu][lane] = hsv;          // publish h3
    __syncthreads();

    // L4: waves 0..5, col = wvu; exact R8 serial-chain order
    if (wvu < 6){
        float a = b4[wvu];
#pragma unroll
        for (int q=0;q<16;q++){
            f32x4 t = hb4[q][lane];
#pragma unroll
            for (int j=0;j<4;j++)
                a = fmaf(t[j], W4[(4*q+j)*6 + wvu], a);
        }
        latb[lane*8+wvu] = a;
    }
    __syncthreads();

    // ---------------- search phase: 8 threads per row (waves 0..7) ----------------
    if (tid >= 512) return;    // no barriers below

    const int row = tid >> 3;        // 0..63
    const int cg  = tid & 7;
    const int rw  = (tid >> 3) & 7;  // row-group within wave
    const int rowg2 = blockIdx.x*64 + row;

    const float lat0=latb[row*8+0], lat1=latb[row*8+1], lat2=latb[row*8+2];
    const float lat3=latb[row*8+3], lat4=latb[row*8+4], lat5=latb[row*8+5];
    const float x3 = latb[row*8+6];

    float rr   = 4e-8f * __expf(lat0);
    float epsv = rcpf(1.0f + __expf(-lat1));
    float Kdl  = __expf(lat2);
    float Deff = 1.91e-9f * epsv * sqrtf(epsv);
    float Kgdl = Kdl * Deff * rcpf(rr);
    float S    = rcpf(Kgdl) + fabsf(x3) * rcpf((1.0f - epsv) * Deff);
    float il0  = S * (float)(1.0 / (2.0  * 96485.33 * 34.0));
    float il1  = S * (float)(1.0 / (12.0 * 96485.33 * 34.0));

    float t0s = 2.0f*lat3, t1s = 2.0f*lat4, t2s = 2.0f*lat5;
    float mx = fmaxf(t0s, fmaxf(t1s, t2s));
    float e0 = __expf(t0s-mx), e1 = __expf(t1s-mx), e2 = __expf(t2s-mx);
    float se = e0 + e1 + e2;
    float it0 = se*rcpf(e0), it1 = se*rcpf(e1), it2 = se*rcpf(e2);

    auto itot = [&](int v) -> float {
        f32x4 tb = *(const f32x4*)&tab4[v*4];
        return rcpf(fmaf(tb.x, it0, il0)) + rcpf(fmaf(tb.y, it1, il1)) + rcpf(tb.z*it2);
    };

    // i_tot strictly decreasing in v (2%/step >> float noise).
    bool le0f = itot(0)   <= 200.0f;
    bool le9f = itot(999) <= 200.0f;

    int lo = 0, hi = 999;
#pragma unroll 1
    for (int rd = 0; rd < 3; ++rd){
        int L = hi - lo;
        int p = lo + (L*(cg+1))/9;
        bool le = itot(p) <= 200.0f;
        unsigned long long bal = __ballot(le);
        unsigned m8 = (unsigned)((bal >> (8*rw)) & 0xFFull);
        int tz  = (m8 == 0u) ? 8 : (int)__builtin_ctz(m8);
        int nlo = (tz > 0) ? lo + (L*tz)/9 : lo;
        int nhi = (tz < 8) ? lo + (L*(tz+1))/9 : hi;
        lo = nlo; hi = nhi;
    }
    // interval now <= 2 wide; one unconditional bisect step (no-op at width 1)
    {
        int mid = lo + ((hi-lo)>>1);
        bool lem = itot(mid) <= 200.0f;
        hi = lem ? mid : hi;
        lo = lem ? lo  : mid;
    }
    float da = itot(lo) - 200.0f;   // > 0 under invariant
    float db = 200.0f - itot(hi);   // >= 0
    int idx = (da <= db) ? lo : hi; // tie -> earlier index (argmin-first)
    if (!le9f) idx = 999;
    if (le0f)  idx = 0;

    f32x4 tb = *(const f32x4*)&tab4[idx*4];
    float s0 = rcpf(fmaf(tb.x, it0, il0));
    float s1 = rcpf(fmaf(tb.y, it1, il1));
    float s2 = rcpf(tb.z*it2);
    float inv = rcpf(s0 + s1 + s2);

    if (cg == 0 && rowg2 < nrows){
        float2 o; o.x = s1*inv; o.y = s0*inv;
        reinterpret_cast<float2*>(out)[rowg2] = o;
    }
}

extern "C" void kernel_launch(void* const* d_in, const int* in_sizes, int n_in,
                              void* d_out, int out_size, void* d_ws, size_t ws_size,
                              hipStream_t stream) {
    (void)n_in; (void)d_ws; (void)ws_size; (void)out_size;
    int nrows = in_sizes[0] / 5;
    int nblk = (nrows + 63) / 64;
    phys9<<<dim3(nblk), dim3(1024), 0, stream>>>(
        (const float*)d_in[0],
        (const float*)d_in[1], (const float*)d_in[2],
        (const float*)d_in[3], (const float*)d_in[4],
        (const float*)d_in[5], (const float*)d_in[6],
        (const float*)d_in[7], (const float*)d_in[8],
        (const float*)d_in[9], (const float*)d_in[10],
        (float*)d_out, nrows);
}